// Round 2
// baseline (12411.446 us; speedup 1.0000x reference)
//
#include <hip/hip_runtime.h>
#include <stdint.h>

// Must match numpy float32 rounding exactly: (dx*dx + dy*dy) + dz*dz, no FMA.
#pragma clang fp contract(off)

#define NPT      2048
#define NBATCH   32
#define NPTS     65536
#define MEMBERS  8
#define NTHREADS 512
#define CHUNK    (NPTS / MEMBERS)       // 8192 points per block
#define PPT      (CHUNK / NTHREADS)     // 16 points per thread

__device__ __forceinline__ uint32_t f2u(float f) { return __float_as_uint(f); }
__device__ __forceinline__ float u2f(uint32_t u) { return __uint_as_float(u); }

__global__ void __launch_bounds__(NTHREADS, 2)
fps_kernel(const float* __restrict__ xyz, int* __restrict__ out,
           uint32_t* __restrict__ ws)
{
    // ws layout: bar[NBATCH][16] (zeroed by memset), then cand[NBATCH][2][MEMBERS][8]
    uint32_t* bar  = ws;
    uint32_t* cand = ws + NBATCH * 16;

    // Swizzle so a batch's 8 member blocks share blockIdx%8 (same XCD if
    // round-robin mapping holds — perf heuristic only, correctness is
    // guaranteed by agent-scope atomics + full co-residency).
    const int i = blockIdx.x;
    const int q = i >> 3;
    const int batch  = (i & 7) * 4 + (q & 3);   // [0,32)
    const int member = q >> 2;                  // [0,8)
    const int tid  = threadIdx.x;
    const int lane = tid & 63;
    const int wv   = tid >> 6;

    const float* xb = xyz + (size_t)batch * 3 * NPTS;
    const int base = member * CHUNK;
    const int idx0 = base + tid;

    // All point data lives in registers: 64 VGPRs of data per thread.
    float px[PPT], py[PPT], pz[PPT], pd[PPT];
#pragma unroll
    for (int k = 0; k < PPT; ++k) {
        int p = idx0 + k * NTHREADS;
        px[k] = xb[p];
        py[k] = xb[NPTS + p];
        pz[k] = xb[2 * NPTS + p];
        pd[k] = 1e10f;
    }

    // First centroid is point 0; first emitted index is 0.
    float cx = xb[0], cy = xb[NPTS], cz = xb[2 * NPTS];
    if (member == 0 && tid == 0) out[batch * NPT] = 0;

    __shared__ uint32_t red[NTHREADS / 64][2];
    __shared__ uint32_t bc[3];

    uint32_t* mybar = bar + batch * 16;
    uint32_t target = 0;

    for (int t = 0; t < NPT - 1; ++t) {
        // ---- dist update + per-thread argmax (first-occurrence: strict >,
        //      ascending k = ascending global index within a thread) ----
        float bv = -1.0f;            // all dists >= 0, so always beaten
        int   bi = 0x7fffffff;
#pragma unroll
        for (int k = 0; k < PPT; ++k) {
            float dx = px[k] - cx;
            float dy = py[k] - cy;
            float dz = pz[k] - cz;
            float d  = dx * dx + dy * dy;   // contract(off): mul,mul,add
            d = d + dz * dz;                // then add — matches numpy order
            float nd = fminf(pd[k], d);
            pd[k] = nd;
            bool g = nd > bv;
            bv = g ? nd : bv;
            bi = g ? (idx0 + k * NTHREADS) : bi;
        }

        // ---- wave argmax-reduce (larger value wins; tie -> smaller index) ----
#pragma unroll
        for (int off = 1; off < 64; off <<= 1) {
            float ov = __shfl_xor(bv, off, 64);
            int   oi = __shfl_xor(bi, off, 64);
            if (ov > bv || (ov == bv && oi < bi)) { bv = ov; bi = oi; }
        }
        if (lane == 0) { red[wv][0] = f2u(bv); red[wv][1] = (uint32_t)bi; }
        __syncthreads();

        target += MEMBERS;   // uniform across all threads

        if (wv == 0) {
            // cross-wave reduce on lanes 0..7
            float v2 = -1.0f; int i2 = 0x7fffffff;
            if (lane < NTHREADS / 64) { v2 = u2f(red[lane][0]); i2 = (int)red[lane][1]; }
#pragma unroll
            for (int off = 4; off >= 1; off >>= 1) {
                float ov = __shfl_xor(v2, off, 64);
                int   oi = __shfl_xor(i2, off, 64);
                if (ov > v2 || (ov == v2 && oi < i2)) { v2 = ov; i2 = oi; }
            }

            // publish block-best (double-buffered by parity), arrive at barrier
            uint32_t* slotbase = cand + (size_t)(batch * 2 + (t & 1)) * MEMBERS * 8;
            if (lane == 0) {
                uint32_t* s = slotbase + member * 8;
                __hip_atomic_store(s + 0, f2u(v2), __ATOMIC_RELAXED, __HIP_MEMORY_SCOPE_AGENT);
                __hip_atomic_store(s + 1, (uint32_t)i2, __ATOMIC_RELAXED, __HIP_MEMORY_SCOPE_AGENT);
                __hip_atomic_fetch_add(mybar, 1u, __ATOMIC_RELEASE, __HIP_MEMORY_SCOPE_AGENT);
                // counting barrier: wait until all 8 members arrived this iter
                while (__hip_atomic_load(mybar, __ATOMIC_ACQUIRE, __HIP_MEMORY_SCOPE_AGENT) < target) {}
            }
            // wave reconverges here after lane 0's spin exits

            // lanes 0..7 read the 8 candidates, reduce to the global winner
            float wvv = -1.0f; int wi = 0x7fffffff;
            if (lane < MEMBERS) {
                uint32_t* s = slotbase + lane * 8;
                wvv = u2f(__hip_atomic_load(s + 0, __ATOMIC_RELAXED, __HIP_MEMORY_SCOPE_AGENT));
                wi  = (int)__hip_atomic_load(s + 1, __ATOMIC_RELAXED, __HIP_MEMORY_SCOPE_AGENT);
            }
#pragma unroll
            for (int off = 4; off >= 1; off >>= 1) {
                float ov = __shfl_xor(wvv, off, 64);
                int   oi = __shfl_xor(wi, off, 64);
                if (ov > wvv || (ov == wvv && oi < wi)) { wvv = ov; wi = oi; }
            }
            if (lane == 0) {
                // fetch winner coords from global (xyz is read-only, L2-resident)
                bc[0] = f2u(xb[wi]);
                bc[1] = f2u(xb[NPTS + wi]);
                bc[2] = f2u(xb[2 * NPTS + wi]);
                if (member == 0) out[batch * NPT + t + 1] = wi;
            }
        }
        __syncthreads();
        cx = u2f(bc[0]); cy = u2f(bc[1]); cz = u2f(bc[2]);
    }
}

extern "C" void kernel_launch(void* const* d_in, const int* in_sizes, int n_in,
                              void* d_out, int out_size, void* d_ws, size_t ws_size,
                              hipStream_t stream)
{
    const float* xyz = (const float*)d_in[0];
    int* out = (int*)d_out;
    uint32_t* ws = (uint32_t*)d_ws;
    // zero only the barrier counters (candidates are always written before read)
    (void)hipMemsetAsync(d_ws, 0, NBATCH * 16 * sizeof(uint32_t), stream);
    fps_kernel<<<NBATCH * MEMBERS, NTHREADS, 0, stream>>>(xyz, out, ws);
}